// Round 11
// baseline (34040.479 us; speedup 1.0000x reference)
//
#include <hip/hip_runtime.h>
#include <hip/hip_bf16.h>

#define B_ 128
#define T_ 1024
#define I_ 256
#define H_ 1024
#define O_ 128
#define NWG 256

typedef __attribute__((ext_vector_type(4))) float f32x4;
typedef __attribute__((ext_vector_type(8))) short s16x8;

__device__ __forceinline__ unsigned short f2bf(float f){
  union { float f; unsigned int u; } a; a.f = f;
  unsigned int r = a.u + 0x7FFFu + ((a.u >> 16) & 1u);
  return (unsigned short)(r >> 16);
}
__device__ __forceinline__ float sigmf(float x){ return 1.f/(1.f+__expf(-x)); }
__device__ __forceinline__ float tanhf_(float x){ return 2.f/(1.f+__expf(-2.f*x)) - 1.f; }

// h-fragment loads: CACHED (L2). Coherence = sc1 stores (write-through to L3)
// + per-phase acquire fence (buffer_inv) after the grid barrier.
__device__ __forceinline__ void ld_frag(s16x8 &d, const unsigned short* p){
  asm volatile("global_load_dwordx4 %0, %1, off" : "=v"(d) : "v"(p) : "memory");
}
// hfin read stays L3-direct (written sc1 at p==T_, read once)
__device__ __forceinline__ void ld_f4c(f32x4 &d, const float* p){
  asm volatile("global_load_dwordx4 %0, %1, off sc1" : "=v"(d) : "v"(p) : "memory");
}
__device__ __forceinline__ void st_h(unsigned short* p, unsigned short v){
  __hip_atomic_store(p, v, __ATOMIC_RELAXED, __HIP_MEMORY_SCOPE_AGENT);
}
__device__ __forceinline__ void st_f(float* p, float v){
  __hip_atomic_store(p, v, __ATOMIC_RELAXED, __HIP_MEMORY_SCOPE_AGENT);
}

template<int N>
__device__ __forceinline__ void waitpair(s16x8 &x, s16x8 &y){
  if      constexpr (N==14) asm volatile("s_waitcnt vmcnt(14)" : "+v"(x), "+v"(y) :: "memory");
  else if constexpr (N==12) asm volatile("s_waitcnt vmcnt(12)" : "+v"(x), "+v"(y) :: "memory");
  else if constexpr (N==10) asm volatile("s_waitcnt vmcnt(10)" : "+v"(x), "+v"(y) :: "memory");
  else if constexpr (N==8)  asm volatile("s_waitcnt vmcnt(8)"  : "+v"(x), "+v"(y) :: "memory");
  else if constexpr (N==6)  asm volatile("s_waitcnt vmcnt(6)"  : "+v"(x), "+v"(y) :: "memory");
  else if constexpr (N==4)  asm volatile("s_waitcnt vmcnt(4)"  : "+v"(x), "+v"(y) :: "memory");
  else if constexpr (N==2)  asm volatile("s_waitcnt vmcnt(2)"  : "+v"(x), "+v"(y) :: "memory");
  else                      asm volatile("s_waitcnt vmcnt(0)"  : "+v"(x), "+v"(y) :: "memory");
}
__device__ __forceinline__ void vm_drain(){
  asm volatile("s_waitcnt vmcnt(0)" ::: "memory");
}

// ---- sharded grid barrier (R9-validated): one barrier per phase ---------
__device__ __forceinline__ void bar_arrive(unsigned* base, int gwg, int tid){
  vm_drain();
  __syncthreads();
  if (tid == 0)
    __hip_atomic_fetch_add(&base[(gwg & 7) << 6], 1u, __ATOMIC_RELAXED, __HIP_MEMORY_SCOPE_AGENT);
}
__device__ __forceinline__ void bar_wait(unsigned* base, unsigned tgt32, int tid){
  if (tid < 8){
    while (__hip_atomic_load(&base[tid << 6], __ATOMIC_RELAXED, __HIP_MEMORY_SCOPE_AGENT) < tgt32)
      __builtin_amdgcn_s_sleep(2);
  }
  __syncthreads();
}

// ---- prep kernels (R4 byte-identical) -----------------------------------

__global__ void k_cast_x(const float* __restrict__ x, unsigned short* __restrict__ xb, int n4){
  int i = blockIdx.x*blockDim.x + threadIdx.x;
  if (i >= n4) return;
  f32x4 v = reinterpret_cast<const f32x4*>(x)[i];
  ushort4 o;
  o.x = f2bf(v[0]); o.y = f2bf(v[1]); o.z = f2bf(v[2]); o.w = f2bf(v[3]);
  reinterpret_cast<ushort4*>(xb)[i] = o;
}

// W0cat layout: [wg 256][kblk 160][row 16][8] bf16, k = [w_ih0 (256) | w_hh0 (1024)]
__global__ void k_prep_w0(const float* __restrict__ wih, const float* __restrict__ whh,
                          unsigned short* __restrict__ out){
  int n = blockIdx.x*256 + threadIdx.x;           // 5242880
  int j = n & 7, r = (n >> 3) & 15;
  int t = n >> 7;
  int kb = t % 160, gw = t / 160;
  int k = kb*8 + j;
  int grow = (r >> 2)*H_ + gw*4 + (r & 3);
  float v = (k < I_) ? wih[grow*I_ + k] : whh[grow*H_ + (k - I_)];
  out[n] = f2bf(v);
}

// W1cat layout: [wg 256][kblk 256][row 16][8] bf16, k = [w_ih1 (1024) | w_hh1 (1024)]
__global__ void k_prep_w1(const float* __restrict__ wih, const float* __restrict__ whh,
                          unsigned short* __restrict__ out){
  int n = blockIdx.x*256 + threadIdx.x;           // 8388608
  int j = n & 7, r = (n >> 3) & 15;
  int t = n >> 7;
  int kb = t & 255, gw = t >> 8;
  int k = kb*8 + j;
  int grow = (r >> 2)*H_ + gw*4 + (r & 3);
  float v = (k < H_) ? wih[grow*H_ + k] : whh[grow*H_ + (k - H_)];
  out[n] = f2bf(v);
}

__global__ void k_prep_b(const float* __restrict__ bi0, const float* __restrict__ bh0,
                         const float* __restrict__ bi1, const float* __restrict__ bh1,
                         float* __restrict__ b0, float* __restrict__ b1){
  int n = blockIdx.x*256 + threadIdx.x;           // 8192
  int layer = n >> 12; int rem = n & 4095;
  int gw = rem >> 4, r = rem & 15;
  int grow = (r >> 2)*H_ + gw*4 + (r & 3);
  if (layer == 0) b0[rem] = bi0[grow] + bh0[grow];
  else            b1[rem] = bi1[grow] + bh1[grow];
}

// ---- persistent LSTM kernel --------------------------------------------

struct KArgs {
  const unsigned short* xb;
  const float* x32;
  const unsigned short* w0l;
  const unsigned short* w1l;
  const float* b0l;
  const float* b1l;
  unsigned short* h0;         // [3][B][H] bf16 ring
  unsigned short* h1;         // [3][B][H] bf16 ring
  float* hfin;
  const float* wout;
  const float* bout;
  float* y;
  unsigned* cnt;              // 8 shards, 256B apart
};

// In-register gate epilogue (R4 verbatim).
__device__ __forceinline__ void epi(f32x4 (&acc)[2], float (&cs)[2][4], float bias,
                                    unsigned short* __restrict__ hw,
                                    float* __restrict__ hfin,
                                    int wv, int lane, int gwg){
  const int u  = lane & 3;
  const int g0 = (lane >> 2) & 3;
  const int bq = lane >> 4;
  #pragma unroll
  for (int btl = 0; btl < 2; ++btl){
    #pragma unroll
    for (int r = 0; r < 4; ++r){
      float pre = acc[btl][r] + bias;
      float q1 = __shfl_xor(pre, 4);
      float q2 = __shfl_xor(pre, 8);
      float q3 = __shfl_xor(pre, 12);
      float iv = (g0==0)?pre:((g0==1)?q1:((g0==2)?q2:q3));
      float fv = (g0==1)?pre:((g0==0)?q1:((g0==3)?q2:q3));
      float gv = (g0==2)?pre:((g0==3)?q1:((g0==0)?q2:q3));
      float ov = (g0==3)?pre:((g0==2)?q1:((g0==1)?q2:q3));
      iv = sigmf(iv); fv = sigmf(fv); gv = tanhf_(gv); ov = sigmf(ov);
      float cn = fv*cs[btl][r] + iv*gv;
      cs[btl][r] = cn;
      float h = ov*tanhf_(cn);
      if (g0 == 0){
        int idx = ((wv*2+btl)*16 + bq*4 + r)*H_ + (gwg<<2) + u;
        st_h(&hw[idx], f2bf(h));
        if (hfin) st_f(&hfin[idx], h);
      }
    }
  }
}

// R4/R8/R9-verbatim pipeline step macros (2 MFMA/step, 8-slot ring, counted)
#define STEP0(i, NW) { \
  const int s_ = (i) & 7; \
  s16x8 wfn_ = wfc; \
  if ((i) + 1 < 32) wfn_ = *(const s16x8*)(sW0 + ((9 + (i)) << 9) + (lane << 3)); \
  waitpair<NW>(fr[s_][0], fr[s_][1]); \
  acc0[0] = __builtin_amdgcn_mfma_f32_16x16x32_bf16(fr[s_][0], wfc, acc0[0], 0, 0, 0); \
  acc0[1] = __builtin_amdgcn_mfma_f32_16x16x32_bf16(fr[s_][1], wfc, acc0[1], 0, 0, 0); \
  if ((i) + 8 < 32){ \
    ld_frag(fr[s_][0], h0r + hoff0 + (((i) + 8) << 5)); \
    ld_frag(fr[s_][1], h0r + hoff1 + (((i) + 8) << 5)); } \
  wfc = wfn_; }

#define STEP1(i, NW) { \
  const int s_ = (i) & 7; \
  s16x8 wfn_ = wfc; \
  if ((i) + 1 < 64) wfn_ = *(const s16x8*)(sW1 + (((i) + 1) << 9) + (lane << 3)); \
  waitpair<NW>(fr[s_][0], fr[s_][1]); \
  acc1[0] = __builtin_amdgcn_mfma_f32_16x16x32_bf16(fr[s_][0], wfc, acc1[0], 0, 0, 0); \
  acc1[1] = __builtin_amdgcn_mfma_f32_16x16x32_bf16(fr[s_][1], wfc, acc1[1], 0, 0, 0); \
  if ((i) + 8 < 64){ const int j_ = (i) + 8; \
    const unsigned short* b_ = (j_ < 32) ? h0r : h1r; \
    ld_frag(fr[s_][0], b_ + hoff0 + ((j_ & 31) << 5)); \
    ld_frag(fr[s_][1], b_ + hoff1 + ((j_ & 31) << 5)); } \
  wfc = wfn_; }

__global__ void __launch_bounds__(256, 1) k_lstm(KArgs a){
  extern __shared__ char smem[];
  unsigned short* sW0 = (unsigned short*)smem;             // 40960 B
  unsigned short* sW1 = (unsigned short*)(smem + 40960);   // 65536 B -> 106496
  float* sB    = (float*)(smem + 106496);                  // 32 f -> 106624 total

  const int tid  = threadIdx.x;
  const int gwg  = blockIdx.x;
  const int wv   = tid >> 6;
  const int lane = tid & 63;
  const int lrow = lane & 15;
  const int kgrp = lane >> 4;
  const int koff = kgrp << 3;

  {
    const s16x8* s0 = (const s16x8*)a.w0l + gwg*2560;
    s16x8* d0 = (s16x8*)sW0;
    for (int i = tid; i < 2560; i += 256) d0[i] = s0[i];
    const s16x8* s1 = (const s16x8*)a.w1l + gwg*4096;
    s16x8* d1 = (s16x8*)sW1;
    for (int i = tid; i < 4096; i += 256) d1[i] = s1[i];
    if (tid < 16){ sB[tid] = a.b0l[gwg*16 + tid]; sB[16 + tid] = a.b1l[gwg*16 + tid]; }
  }
  __syncthreads();

  const float bias0 = sB[lrow];
  const float bias1 = sB[16 + lrow];
  float c0s[2][4] = {{0,0,0,0},{0,0,0,0}};
  float c1s[2][4] = {{0,0,0,0},{0,0,0,0}};

  const int hoff0 = ((wv*2 + 0)*16 + lrow)*H_ + koff;
  const int hoff1 = ((wv*2 + 1)*16 + lrow)*H_ + koff;
  const size_t xoff0 = (size_t)((wv*2 + 0)*16 + lrow)*(T_*I_) + koff;
  const size_t xoff1 = (size_t)((wv*2 + 1)*16 + lrow)*(T_*I_) + koff;
  const f32x4 z = {0.f, 0.f, 0.f, 0.f};

  int m3 = 0, m3p1 = 1, m3p2 = 2;   // R4-proven ring-3

  for (int p = 0; p <= T_; ++p){
    const unsigned short* __restrict__ h0r = a.h0 + m3p2*(B_*H_);  // h0_{p-1}
    const unsigned short* __restrict__ h1r = a.h1 + m3p1*(B_*H_);  // h1_{p-2}
    unsigned short* __restrict__ h0w = a.h0 + m3  *(B_*H_);        // h0_p
    unsigned short* __restrict__ h1w = a.h1 + m3p2*(B_*H_);        // h1_{p-1}

    // ---- L0 x-part hoisted above the wait (barrier-independent work) ----
    f32x4 acc0[2] = {z, z};
    if (p < T_){
      if (a.xb){
        const unsigned short* xp0 = a.xb + xoff0 + p*I_;
        const unsigned short* xp1 = a.xb + xoff1 + p*I_;
        #pragma unroll
        for (int kc = 0; kc < 8; ++kc){
          s16x8 wf = *(const s16x8*)(sW0 + (kc << 9) + (lane << 3));
          s16x8 a0 = *(const s16x8*)(xp0 + (kc << 5));
          s16x8 a1 = *(const s16x8*)(xp1 + (kc << 5));
          acc0[0] = __builtin_amdgcn_mfma_f32_16x16x32_bf16(a0, wf, acc0[0], 0, 0, 0);
          acc0[1] = __builtin_amdgcn_mfma_f32_16x16x32_bf16(a1, wf, acc0[1], 0, 0, 0);
        }
      } else {
        const float* fx0 = a.x32 + xoff0 + p*I_;
        const float* fx1 = a.x32 + xoff1 + p*I_;
        #pragma unroll
        for (int kc = 0; kc < 8; ++kc){
          s16x8 wf = *(const s16x8*)(sW0 + (kc << 9) + (lane << 3));
          union { s16x8 v; unsigned short us[8]; } t0, t1;
          f32x4 p00 = *(const f32x4*)(fx0 + (kc << 5));
          f32x4 p01 = *(const f32x4*)(fx0 + (kc << 5) + 4);
          f32x4 p10 = *(const f32x4*)(fx1 + (kc << 5));
          f32x4 p11 = *(const f32x4*)(fx1 + (kc << 5) + 4);
          #pragma unroll
          for (int j2 = 0; j2 < 4; ++j2){
            t0.us[j2] = f2bf(p00[j2]); t0.us[4+j2] = f2bf(p01[j2]);
            t1.us[j2] = f2bf(p10[j2]); t1.us[4+j2] = f2bf(p11[j2]);
          }
          acc0[0] = __builtin_amdgcn_mfma_f32_16x16x32_bf16(t0.v, wf, acc0[0], 0, 0, 0);
          acc0[1] = __builtin_amdgcn_mfma_f32_16x16x32_bf16(t1.v, wf, acc0[1], 0, 0, 0);
        }
      }
    }

    // ---- single wait: all WGs completed phase p-1; then invalidate L2 ----
    if (p > 0){
      bar_wait(a.cnt, 32u * (unsigned)p, tid);
      __builtin_amdgcn_fence(__ATOMIC_ACQUIRE, "agent");   // buffer_inv: L2 refetch of h
    }

    if (p < T_){
      vm_drain();   // counted region must contain only our asm loads
      s16x8 fr[8][2];
      #pragma unroll
      for (int s2 = 0; s2 < 8; ++s2){
        ld_frag(fr[s2][0], h0r + hoff0 + (s2 << 5));
        ld_frag(fr[s2][1], h0r + hoff1 + (s2 << 5));
      }
      s16x8 wfc = *(const s16x8*)(sW0 + (8 << 9) + (lane << 3));
      #pragma unroll
      for (int i = 0; i < 25; ++i) STEP0(i, 14);
      STEP0(25,12); STEP0(26,10); STEP0(27,8); STEP0(28,6);
      STEP0(29,4);  STEP0(30,2);  STEP0(31,0);
      epi(acc0, c0s, bias0, h0w, nullptr, wv, lane, gwg);
    }

    if (p > 0){
      // ---- layer 1, step p-1: gates1 = [h0_{p-1} | h1_{p-2}] @ W1cat^T ----
      f32x4 acc1[2] = {z, z};
      vm_drain();   // clear epi stores / x loads from the count
      s16x8 fr[8][2];
      #pragma unroll
      for (int s2 = 0; s2 < 8; ++s2){
        ld_frag(fr[s2][0], h0r + hoff0 + (s2 << 5));
        ld_frag(fr[s2][1], h0r + hoff1 + (s2 << 5));
      }
      s16x8 wfc = *(const s16x8*)(sW1 + (lane << 3));
      #pragma unroll
      for (int i = 0; i < 57; ++i) STEP1(i, 14);
      STEP1(57,12); STEP1(58,10); STEP1(59,8); STEP1(60,6);
      STEP1(61,4);  STEP1(62,2);  STEP1(63,0);
      epi(acc1, c1s, bias1, h1w, (p == T_) ? a.hfin : nullptr, wv, lane, gwg);
    }

    bar_arrive(a.cnt, gwg, tid);     // single end-of-phase publish

    m3 = m3p1; m3p1 = m3p2; m3p2 = (m3p2 == 2) ? 0 : m3p2 + 1;
  }

  bar_wait(a.cnt, 32u * (unsigned)(T_ + 1), tid);

  // output: y = h_last @ w_out^T + b_out (fp32) on WGs 0..63 (R4 verbatim)
  if (gwg < 64){
    const int b = (gwg >> 3)*16 + (tid >> 4);
    const int o = (gwg & 7)*16 + (tid & 15);
    const float* hb = a.hfin + b*H_;
    const f32x4* wr = (const f32x4*)(a.wout + o*H_);
    float s = a.bout[o];
    for (int g = 0; g < 32; ++g){
      f32x4 t0,t1,t2,t3,t4,t5,t6,t7;
      ld_f4c(t0, hb + g*32 +  0); ld_f4c(t1, hb + g*32 +  4);
      ld_f4c(t2, hb + g*32 +  8); ld_f4c(t3, hb + g*32 + 12);
      ld_f4c(t4, hb + g*32 + 16); ld_f4c(t5, hb + g*32 + 20);
      ld_f4c(t6, hb + g*32 + 24); ld_f4c(t7, hb + g*32 + 28);
      asm volatile("s_waitcnt vmcnt(0)"
        : "+v"(t0),"+v"(t1),"+v"(t2),"+v"(t3),"+v"(t4),"+v"(t5),"+v"(t6),"+v"(t7) :: "memory");
      const f32x4 w0 = wr[g*8+0], w1 = wr[g*8+1], w2 = wr[g*8+2], w3 = wr[g*8+3];
      const f32x4 w4 = wr[g*8+4], w5 = wr[g*8+5], w6 = wr[g*8+6], w7 = wr[g*8+7];
      s += t0[0]*w0[0]+t0[1]*w0[1]+t0[2]*w0[2]+t0[3]*w0[3];
      s += t1[0]*w1[0]+t1[1]*w1[1]+t1[2]*w1[2]+t1[3]*w1[3];
      s += t2[0]*w2[0]+t2[1]*w2[1]+t2[2]*w2[2]+t2[3]*w2[3];
      s += t3[0]*w3[0]+t3[1]*w3[1]+t3[2]*w3[2]+t3[3]*w3[3];
      s += t4[0]*w4[0]+t4[1]*w4[1]+t4[2]*w4[2]+t4[3]*w4[3];
      s += t5[0]*w5[0]+t5[1]*w5[1]+t5[2]*w5[2]+t5[3]*w5[3];
      s += t6[0]*w6[0]+t6[1]*w6[1]+t6[2]*w6[2]+t6[3]*w6[3];
      s += t7[0]*w7[0]+t7[1]*w7[1]+t7[2]*w7[2]+t7[3]*w7[3];
    }
    a.y[b*O_ + o] = s;
  }
}

// ---- host ---------------------------------------------------------------

extern "C" void kernel_launch(void* const* d_in, const int* in_sizes, int n_in,
                              void* d_out, int out_size, void* d_ws, size_t ws_size,
                              hipStream_t stream){
  const float* x    = (const float*)d_in[0];
  const float* wih0 = (const float*)d_in[1];
  const float* whh0 = (const float*)d_in[2];
  const float* bih0 = (const float*)d_in[3];
  const float* bhh0 = (const float*)d_in[4];
  const float* wih1 = (const float*)d_in[5];
  const float* whh1 = (const float*)d_in[6];
  const float* bih1 = (const float*)d_in[7];
  const float* bhh1 = (const float*)d_in[8];
  const float* wout = (const float*)d_in[9];
  const float* bout = (const float*)d_in[10];
  float* y = (float*)d_out;

  char* ws = (char*)d_ws;
  size_t off = 0;
  auto alloc = [&](size_t n){ char* p = ws + off; off += (n + 255) & ~(size_t)255; return p; };

  unsigned* cnt = (unsigned*)alloc(2048);           // 8 shards, 256B apart
  unsigned short* w0l = (unsigned short*)alloc((size_t)256*160*16*8*2);
  unsigned short* w1l = (unsigned short*)alloc((size_t)256*256*16*8*2);
  float* b0l  = (float*)alloc(256*16*4);
  float* b1l  = (float*)alloc(256*16*4);
  unsigned short* h0 = (unsigned short*)alloc((size_t)3*B_*H_*2);
  unsigned short* h1 = (unsigned short*)alloc((size_t)3*B_*H_*2);
  float* hfin = (float*)alloc((size_t)B_*H_*4);
  unsigned short* xb = nullptr;
  size_t xb_bytes = (size_t)B_*T_*I_*2;
  if (ws_size >= off + xb_bytes + 256) xb = (unsigned short*)alloc(xb_bytes);

  hipMemsetAsync(cnt, 0, 2048, stream);
  hipMemsetAsync(h0, 0, (size_t)3*B_*H_*2, stream);
  hipMemsetAsync(h1, 0, (size_t)3*B_*H_*2, stream);

  if (xb) k_cast_x<<<dim3((B_*T_*I_/4 + 255)/256), dim3(256), 0, stream>>>(x, xb, B_*T_*I_/4);
  k_prep_w0<<<dim3(5242880/256), dim3(256), 0, stream>>>(wih0, whh0, w0l);
  k_prep_w1<<<dim3(8388608/256), dim3(256), 0, stream>>>(wih1, whh1, w1l);
  k_prep_b<<<dim3(32), dim3(256), 0, stream>>>(bih0, bhh0, bih1, bhh1, b0l, b1l);

  KArgs args;
  args.xb = xb; args.x32 = x;
  args.w0l = w0l; args.w1l = w1l; args.b0l = b0l; args.b1l = b1l;
  args.h0 = h0; args.h1 = h1; args.hfin = hfin;
  args.wout = wout; args.bout = bout; args.y = y;
  args.cnt = cnt;

  (void)hipFuncSetAttribute((const void*)k_lstm,
                            hipFuncAttributeMaxDynamicSharedMemorySize, 106624);
  void* kp[] = { (void*)&args };
  hipLaunchCooperativeKernel((void*)k_lstm, dim3(NWG), dim3(256), kp, 106624, stream);
}

// Round 13
// 13861.461 us; speedup vs baseline: 2.4558x; 2.4558x over previous
//
#include <hip/hip_runtime.h>
#include <hip/hip_bf16.h>

#define B_ 128
#define T_ 1024
#define I_ 256
#define H_ 1024
#define O_ 128
#define NWG 256
#define HS_ 131072   // ushorts per h slot: [8 rowblk][32 chunk][64 lane][8] = 256KB

typedef __attribute__((ext_vector_type(4))) float f32x4;
typedef __attribute__((ext_vector_type(8))) short s16x8;

__device__ __forceinline__ unsigned short f2bf(float f){
  union { float f; unsigned int u; } a; a.f = f;
  unsigned int r = a.u + 0x7FFFu + ((a.u >> 16) & 1u);
  return (unsigned short)(r >> 16);
}
__device__ __forceinline__ float sigmf(float x){ return 1.f/(1.f+__expf(-x)); }
__device__ __forceinline__ float tanhf_(float x){ return 2.f/(1.f+__expf(-2.f*x)) - 1.f; }

// L3-direct coherent accessors (validated R4/R8/R9)
__device__ __forceinline__ void ld_frag(s16x8 &d, const unsigned short* p){
  asm volatile("global_load_dwordx4 %0, %1, off sc1" : "=v"(d) : "v"(p) : "memory");
}
__device__ __forceinline__ void ld_f4c(f32x4 &d, const float* p){
  asm volatile("global_load_dwordx4 %0, %1, off sc1" : "=v"(d) : "v"(p) : "memory");
}
__device__ __forceinline__ void st_h(unsigned short* p, unsigned short v){
  __hip_atomic_store(p, v, __ATOMIC_RELAXED, __HIP_MEMORY_SCOPE_AGENT);
}
__device__ __forceinline__ void st_f(float* p, float v){
  __hip_atomic_store(p, v, __ATOMIC_RELAXED, __HIP_MEMORY_SCOPE_AGENT);
}

template<int N>
__device__ __forceinline__ void waitpair(s16x8 &x, s16x8 &y){
  if      constexpr (N==14) asm volatile("s_waitcnt vmcnt(14)" : "+v"(x), "+v"(y) :: "memory");
  else if constexpr (N==12) asm volatile("s_waitcnt vmcnt(12)" : "+v"(x), "+v"(y) :: "memory");
  else if constexpr (N==10) asm volatile("s_waitcnt vmcnt(10)" : "+v"(x), "+v"(y) :: "memory");
  else if constexpr (N==8)  asm volatile("s_waitcnt vmcnt(8)"  : "+v"(x), "+v"(y) :: "memory");
  else if constexpr (N==6)  asm volatile("s_waitcnt vmcnt(6)"  : "+v"(x), "+v"(y) :: "memory");
  else if constexpr (N==4)  asm volatile("s_waitcnt vmcnt(4)"  : "+v"(x), "+v"(y) :: "memory");
  else if constexpr (N==2)  asm volatile("s_waitcnt vmcnt(2)"  : "+v"(x), "+v"(y) :: "memory");
  else                      asm volatile("s_waitcnt vmcnt(0)"  : "+v"(x), "+v"(y) :: "memory");
}
__device__ __forceinline__ void vm_drain(){
  asm volatile("s_waitcnt vmcnt(0)" ::: "memory");
}

// ---- sharded grid barrier (R9-validated): one barrier per phase ---------
__device__ __forceinline__ void bar_arrive(unsigned* base, int gwg, int tid){
  vm_drain();
  __syncthreads();
  if (tid == 0)
    __hip_atomic_fetch_add(&base[(gwg & 7) << 6], 1u, __ATOMIC_RELAXED, __HIP_MEMORY_SCOPE_AGENT);
}
__device__ __forceinline__ void bar_wait(unsigned* base, unsigned tgt32, int tid){
  if (tid < 8){
    while (__hip_atomic_load(&base[tid << 6], __ATOMIC_RELAXED, __HIP_MEMORY_SCOPE_AGENT) < tgt32)
      __builtin_amdgcn_s_sleep(2);
  }
  __syncthreads();
}

// ---- prep kernels (R4 byte-identical) -----------------------------------

__global__ void k_cast_x(const float* __restrict__ x, unsigned short* __restrict__ xb, int n4){
  int i = blockIdx.x*blockDim.x + threadIdx.x;
  if (i >= n4) return;
  f32x4 v = reinterpret_cast<const f32x4*>(x)[i];
  ushort4 o;
  o.x = f2bf(v[0]); o.y = f2bf(v[1]); o.z = f2bf(v[2]); o.w = f2bf(v[3]);
  reinterpret_cast<ushort4*>(xb)[i] = o;
}

// W0cat layout: [wg 256][kblk 160][row 16][8] bf16, k = [w_ih0 (256) | w_hh0 (1024)]
__global__ void k_prep_w0(const float* __restrict__ wih, const float* __restrict__ whh,
                          unsigned short* __restrict__ out){
  int n = blockIdx.x*256 + threadIdx.x;           // 5242880
  int j = n & 7, r = (n >> 3) & 15;
  int t = n >> 7;
  int kb = t % 160, gw = t / 160;
  int k = kb*8 + j;
  int grow = (r >> 2)*H_ + gw*4 + (r & 3);
  float v = (k < I_) ? wih[grow*I_ + k] : whh[grow*H_ + (k - I_)];
  out[n] = f2bf(v);
}

// W1cat layout: [wg 256][kblk 256][row 16][8] bf16, k = [w_ih1 (1024) | w_hh1 (1024)]
__global__ void k_prep_w1(const float* __restrict__ wih, const float* __restrict__ whh,
                          unsigned short* __restrict__ out){
  int n = blockIdx.x*256 + threadIdx.x;           // 8388608
  int j = n & 7, r = (n >> 3) & 15;
  int t = n >> 7;
  int kb = t & 255, gw = t >> 8;
  int k = kb*8 + j;
  int grow = (r >> 2)*H_ + gw*4 + (r & 3);
  float v = (k < H_) ? wih[grow*H_ + k] : whh[grow*H_ + (k - H_)];
  out[n] = f2bf(v);
}

__global__ void k_prep_b(const float* __restrict__ bi0, const float* __restrict__ bh0,
                         const float* __restrict__ bi1, const float* __restrict__ bh1,
                         float* __restrict__ b0, float* __restrict__ b1){
  int n = blockIdx.x*256 + threadIdx.x;           // 8192
  int layer = n >> 12; int rem = n & 4095;
  int gw = rem >> 4, r = rem & 15;
  int grow = (r >> 2)*H_ + gw*4 + (r & 3);
  if (layer == 0) b0[rem] = bi0[grow] + bh0[grow];
  else            b1[rem] = bi1[grow] + bh1[grow];
}

// ---- persistent LSTM kernel --------------------------------------------

struct KArgs {
  const unsigned short* xb;
  const float* x32;
  const unsigned short* w0l;
  const unsigned short* w1l;
  const float* b0l;
  const float* b1l;
  unsigned short* h0;         // [3][HS_] fragment-major ring
  unsigned short* h1;         // [3][HS_]
  float* hfin;                // [B][H] fp32 (linear)
  const float* wout;
  const float* bout;
  float* y;
  unsigned* cnt;              // 8 shards, 256B apart
};

// In-register gate epilogue (R4 gate math verbatim; h stored fragment-major).
// hS element for (batch b, unit ug): rb=b>>4, brow=b&15, chunk=ug>>5,
// lane_in=((ug>>3)&3)*16+brow, j=ug&7 -> idx = ((rb*32+chunk)<<9)+lane_in*8+j
__device__ __forceinline__ void epi(f32x4 (&acc)[2], float (&cs)[2][4], float bias,
                                    unsigned short* __restrict__ hw,
                                    float* __restrict__ hfin,
                                    int wv, int lane, int gwg){
  const int u  = lane & 3;
  const int g0 = (lane >> 2) & 3;
  const int bq = lane >> 4;
  const int ug = (gwg << 2) + u;            // global unit 0..1023
  const int kc = ug >> 5;
  const int kg = (ug >> 3) & 3;
  const int jj = ug & 7;
  #pragma unroll
  for (int btl = 0; btl < 2; ++btl){
    const int rb = wv*2 + btl;
    #pragma unroll
    for (int r = 0; r < 4; ++r){
      float pre = acc[btl][r] + bias;
      float q1 = __shfl_xor(pre, 4);
      float q2 = __shfl_xor(pre, 8);
      float q3 = __shfl_xor(pre, 12);
      float iv = (g0==0)?pre:((g0==1)?q1:((g0==2)?q2:q3));
      float fv = (g0==1)?pre:((g0==0)?q1:((g0==3)?q2:q3));
      float gv = (g0==2)?pre:((g0==3)?q1:((g0==0)?q2:q3));
      float ov = (g0==3)?pre:((g0==2)?q1:((g0==1)?q2:q3));
      iv = sigmf(iv); fv = sigmf(fv); gv = tanhf_(gv); ov = sigmf(ov);
      float cn = fv*cs[btl][r] + iv*gv;
      cs[btl][r] = cn;
      float h = ov*tanhf_(cn);
      if (g0 == 0){
        int brow = bq*4 + r;
        int eidx = (((rb*32 + kc) << 9) + (kg*16 + brow)*8 + jj);
        st_h(&hw[eidx], f2bf(h));
        if (hfin) st_f(&hfin[(rb*16 + brow)*H_ + ug], h);
      }
    }
  }
}

// Pipeline step macros: R9 schedule; addresses now fragment-major 1KB blocks.
// rdA/rdB = chunk-block bases (wv*2)*32 and (wv*2+1)*32; l8 = lane*8.
#define STEP0(i, NW) { \
  const int s_ = (i) & 7; \
  s16x8 wfn_ = wfc; \
  if ((i) + 1 < 32) wfn_ = *(const s16x8*)(sW0 + ((9 + (i)) << 9) + (lane << 3)); \
  waitpair<NW>(fr[s_][0], fr[s_][1]); \
  acc0[0] = __builtin_amdgcn_mfma_f32_16x16x32_bf16(fr[s_][0], wfc, acc0[0], 0, 0, 0); \
  acc0[1] = __builtin_amdgcn_mfma_f32_16x16x32_bf16(fr[s_][1], wfc, acc0[1], 0, 0, 0); \
  if ((i) + 8 < 32){ \
    ld_frag(fr[s_][0], h0r + ((rdA + (i) + 8) << 9) + l8); \
    ld_frag(fr[s_][1], h0r + ((rdB + (i) + 8) << 9) + l8); } \
  wfc = wfn_; }

#define STEP1(i, NW) { \
  const int s_ = (i) & 7; \
  s16x8 wfn_ = wfc; \
  if ((i) + 1 < 64) wfn_ = *(const s16x8*)(sW1 + (((i) + 1) << 9) + (lane << 3)); \
  waitpair<NW>(fr[s_][0], fr[s_][1]); \
  acc1[0] = __builtin_amdgcn_mfma_f32_16x16x32_bf16(fr[s_][0], wfc, acc1[0], 0, 0, 0); \
  acc1[1] = __builtin_amdgcn_mfma_f32_16x16x32_bf16(fr[s_][1], wfc, acc1[1], 0, 0, 0); \
  if ((i) + 8 < 64){ const int j_ = (i) + 8; \
    const unsigned short* b_ = (j_ < 32) ? h0r : h1r; \
    ld_frag(fr[s_][0], b_ + ((rdA + (j_ & 31)) << 9) + l8); \
    ld_frag(fr[s_][1], b_ + ((rdB + (j_ & 31)) << 9) + l8); } \
  wfc = wfn_; }

__global__ void __launch_bounds__(256, 1) k_lstm(KArgs a){
  extern __shared__ char smem[];
  unsigned short* sW0 = (unsigned short*)smem;             // 40960 B
  unsigned short* sW1 = (unsigned short*)(smem + 40960);   // 65536 B -> 106496
  float* sB    = (float*)(smem + 106496);                  // 32 f -> 106624 total

  const int tid  = threadIdx.x;
  const int gwg  = blockIdx.x;
  const int wv   = tid >> 6;
  const int lane = tid & 63;
  const int lrow = lane & 15;
  const int kgrp = lane >> 4;
  const int koff = kgrp << 3;

  {
    const s16x8* s0 = (const s16x8*)a.w0l + gwg*2560;
    s16x8* d0 = (s16x8*)sW0;
    for (int i = tid; i < 2560; i += 256) d0[i] = s0[i];
    const s16x8* s1 = (const s16x8*)a.w1l + gwg*4096;
    s16x8* d1 = (s16x8*)sW1;
    for (int i = tid; i < 4096; i += 256) d1[i] = s1[i];
    if (tid < 16){ sB[tid] = a.b0l[gwg*16 + tid]; sB[16 + tid] = a.b1l[gwg*16 + tid]; }
  }
  __syncthreads();

  const float bias0 = sB[lrow];
  const float bias1 = sB[16 + lrow];
  float c0s[2][4] = {{0,0,0,0},{0,0,0,0}};
  float c1s[2][4] = {{0,0,0,0},{0,0,0,0}};

  const int rdA = (wv*2 + 0) << 5;   // chunk-block base, rowblk wv*2
  const int rdB = (wv*2 + 1) << 5;   // rowblk wv*2+1
  const int l8  = lane << 3;
  const size_t xoff0 = (size_t)((wv*2 + 0)*16 + lrow)*(T_*I_) + koff;
  const size_t xoff1 = (size_t)((wv*2 + 1)*16 + lrow)*(T_*I_) + koff;
  const f32x4 z = {0.f, 0.f, 0.f, 0.f};

  int m3 = 0, m3p1 = 1, m3p2 = 2;   // R4-proven ring-3

  for (int p = 0; p <= T_; ++p){
    const unsigned short* __restrict__ h0r = a.h0 + m3p2*HS_;  // h0_{p-1}
    const unsigned short* __restrict__ h1r = a.h1 + m3p1*HS_;  // h1_{p-2}
    unsigned short* __restrict__ h0w = a.h0 + m3  *HS_;        // h0_p
    unsigned short* __restrict__ h1w = a.h1 + m3p2*HS_;        // h1_{p-1}

    // ---- L0 x-part hoisted above the wait (R9 verbatim) ----
    f32x4 acc0[2] = {z, z};
    if (p < T_){
      if (a.xb){
        const unsigned short* xp0 = a.xb + xoff0 + p*I_;
        const unsigned short* xp1 = a.xb + xoff1 + p*I_;
        #pragma unroll
        for (int kc = 0; kc < 8; ++kc){
          s16x8 wf = *(const s16x8*)(sW0 + (kc << 9) + (lane << 3));
          s16x8 a0 = *(const s16x8*)(xp0 + (kc << 5));
          s16x8 a1 = *(const s16x8*)(xp1 + (kc << 5));
          acc0[0] = __builtin_amdgcn_mfma_f32_16x16x32_bf16(a0, wf, acc0[0], 0, 0, 0);
          acc0[1] = __builtin_amdgcn_mfma_f32_16x16x32_bf16(a1, wf, acc0[1], 0, 0, 0);
        }
      } else {
        const float* fx0 = a.x32 + xoff0 + p*I_;
        const float* fx1 = a.x32 + xoff1 + p*I_;
        #pragma unroll
        for (int kc = 0; kc < 8; ++kc){
          s16x8 wf = *(const s16x8*)(sW0 + (kc << 9) + (lane << 3));
          union { s16x8 v; unsigned short us[8]; } t0, t1;
          f32x4 p00 = *(const f32x4*)(fx0 + (kc << 5));
          f32x4 p01 = *(const f32x4*)(fx0 + (kc << 5) + 4);
          f32x4 p10 = *(const f32x4*)(fx1 + (kc << 5));
          f32x4 p11 = *(const f32x4*)(fx1 + (kc << 5) + 4);
          #pragma unroll
          for (int j2 = 0; j2 < 4; ++j2){
            t0.us[j2] = f2bf(p00[j2]); t0.us[4+j2] = f2bf(p01[j2]);
            t1.us[j2] = f2bf(p10[j2]); t1.us[4+j2] = f2bf(p11[j2]);
          }
          acc0[0] = __builtin_amdgcn_mfma_f32_16x16x32_bf16(t0.v, wf, acc0[0], 0, 0, 0);
          acc0[1] = __builtin_amdgcn_mfma_f32_16x16x32_bf16(t1.v, wf, acc0[1], 0, 0, 0);
        }
      }
    }

    // ---- single wait: all WGs completed phase p-1 ----
    if (p > 0) bar_wait(a.cnt, 32u * (unsigned)p, tid);

    if (p < T_){
      vm_drain();   // counted region must contain only our asm loads
      s16x8 fr[8][2];
      #pragma unroll
      for (int s2 = 0; s2 < 8; ++s2){
        ld_frag(fr[s2][0], h0r + ((rdA + s2) << 9) + l8);
        ld_frag(fr[s2][1], h0r + ((rdB + s2) << 9) + l8);
      }
      s16x8 wfc = *(const s16x8*)(sW0 + (8 << 9) + (lane << 3));
      #pragma unroll
      for (int i = 0; i < 25; ++i) STEP0(i, 14);
      STEP0(25,12); STEP0(26,10); STEP0(27,8); STEP0(28,6);
      STEP0(29,4);  STEP0(30,2);  STEP0(31,0);
      epi(acc0, c0s, bias0, h0w, nullptr, wv, lane, gwg);
    }

    if (p > 0){
      // ---- layer 1, step p-1: gates1 = [h0_{p-1} | h1_{p-2}] @ W1cat^T ----
      f32x4 acc1[2] = {z, z};
      vm_drain();   // clear epi stores / x loads from the count
      s16x8 fr[8][2];
      #pragma unroll
      for (int s2 = 0; s2 < 8; ++s2){
        ld_frag(fr[s2][0], h0r + ((rdA + s2) << 9) + l8);
        ld_frag(fr[s2][1], h0r + ((rdB + s2) << 9) + l8);
      }
      s16x8 wfc = *(const s16x8*)(sW1 + (lane << 3));
      #pragma unroll
      for (int i = 0; i < 57; ++i) STEP1(i, 14);
      STEP1(57,12); STEP1(58,10); STEP1(59,8); STEP1(60,6);
      STEP1(61,4);  STEP1(62,2);  STEP1(63,0);
      epi(acc1, c1s, bias1, h1w, (p == T_) ? a.hfin : nullptr, wv, lane, gwg);
    }

    bar_arrive(a.cnt, gwg, tid);     // single end-of-phase publish

    m3 = m3p1; m3p1 = m3p2; m3p2 = (m3p2 == 2) ? 0 : m3p2 + 1;
  }

  bar_wait(a.cnt, 32u * (unsigned)(T_ + 1), tid);

  // output: y = h_last @ w_out^T + b_out (fp32) on WGs 0..63 (R4 verbatim)
  if (gwg < 64){
    const int b = (gwg >> 3)*16 + (tid >> 4);
    const int o = (gwg & 7)*16 + (tid & 15);
    const float* hb = a.hfin + b*H_;
    const f32x4* wr = (const f32x4*)(a.wout + o*H_);
    float s = a.bout[o];
    for (int g = 0; g < 32; ++g){
      f32x4 t0,t1,t2,t3,t4,t5,t6,t7;
      ld_f4c(t0, hb + g*32 +  0); ld_f4c(t1, hb + g*32 +  4);
      ld_f4c(t2, hb + g*32 +  8); ld_f4c(t3, hb + g*32 + 12);
      ld_f4c(t4, hb + g*32 + 16); ld_f4c(t5, hb + g*32 + 20);
      ld_f4c(t6, hb + g*32 + 24); ld_f4c(t7, hb + g*32 + 28);
      asm volatile("s_waitcnt vmcnt(0)"
        : "+v"(t0),"+v"(t1),"+v"(t2),"+v"(t3),"+v"(t4),"+v"(t5),"+v"(t6),"+v"(t7) :: "memory");
      const f32x4 w0 = wr[g*8+0], w1 = wr[g*8+1], w2 = wr[g*8+2], w3 = wr[g*8+3];
      const f32x4 w4 = wr[g*8+4], w5 = wr[g*8+5], w6 = wr[g*8+6], w7 = wr[g*8+7];
      s += t0[0]*w0[0]+t0[1]*w0[1]+t0[2]*w0[2]+t0[3]*w0[3];
      s += t1[0]*w1[0]+t1[1]*w1[1]+t1[2]*w1[2]+t1[3]*w1[3];
      s += t2[0]*w2[0]+t2[1]*w2[1]+t2[2]*w2[2]+t2[3]*w2[3];
      s += t3[0]*w3[0]+t3[1]*w3[1]+t3[2]*w3[2]+t3[3]*w3[3];
      s += t4[0]*w4[0]+t4[1]*w4[1]+t4[2]*w4[2]+t4[3]*w4[3];
      s += t5[0]*w5[0]+t5[1]*w5[1]+t5[2]*w5[2]+t5[3]*w5[3];
      s += t6[0]*w6[0]+t6[1]*w6[1]+t6[2]*w6[2]+t6[3]*w6[3];
      s += t7[0]*w7[0]+t7[1]*w7[1]+t7[2]*w7[2]+t7[3]*w7[3];
    }
    a.y[b*O_ + o] = s;
  }
}

// ---- host ---------------------------------------------------------------

extern "C" void kernel_launch(void* const* d_in, const int* in_sizes, int n_in,
                              void* d_out, int out_size, void* d_ws, size_t ws_size,
                              hipStream_t stream){
  const float* x    = (const float*)d_in[0];
  const float* wih0 = (const float*)d_in[1];
  const float* whh0 = (const float*)d_in[2];
  const float* bih0 = (const float*)d_in[3];
  const float* bhh0 = (const float*)d_in[4];
  const float* wih1 = (const float*)d_in[5];
  const float* whh1 = (const float*)d_in[6];
  const float* bih1 = (const float*)d_in[7];
  const float* bhh1 = (const float*)d_in[8];
  const float* wout = (const float*)d_in[9];
  const float* bout = (const float*)d_in[10];
  float* y = (float*)d_out;

  char* ws = (char*)d_ws;
  size_t off = 0;
  auto alloc = [&](size_t n){ char* p = ws + off; off += (n + 255) & ~(size_t)255; return p; };

  unsigned* cnt = (unsigned*)alloc(2048);           // 8 shards, 256B apart
  unsigned short* w0l = (unsigned short*)alloc((size_t)256*160*16*8*2);
  unsigned short* w1l = (unsigned short*)alloc((size_t)256*256*16*8*2);
  float* b0l  = (float*)alloc(256*16*4);
  float* b1l  = (float*)alloc(256*16*4);
  unsigned short* h0 = (unsigned short*)alloc((size_t)3*HS_*2);
  unsigned short* h1 = (unsigned short*)alloc((size_t)3*HS_*2);
  float* hfin = (float*)alloc((size_t)B_*H_*4);
  unsigned short* xb = nullptr;
  size_t xb_bytes = (size_t)B_*T_*I_*2;
  if (ws_size >= off + xb_bytes + 256) xb = (unsigned short*)alloc(xb_bytes);

  hipMemsetAsync(cnt, 0, 2048, stream);
  hipMemsetAsync(h0, 0, (size_t)3*HS_*2, stream);
  hipMemsetAsync(h1, 0, (size_t)3*HS_*2, stream);

  if (xb) k_cast_x<<<dim3((B_*T_*I_/4 + 255)/256), dim3(256), 0, stream>>>(x, xb, B_*T_*I_/4);
  k_prep_w0<<<dim3(5242880/256), dim3(256), 0, stream>>>(wih0, whh0, w0l);
  k_prep_w1<<<dim3(8388608/256), dim3(256), 0, stream>>>(wih1, whh1, w1l);
  k_prep_b<<<dim3(32), dim3(256), 0, stream>>>(bih0, bhh0, bih1, bhh1, b0l, b1l);

  KArgs args;
  args.xb = xb; args.x32 = x;
  args.w0l = w0l; args.w1l = w1l; args.b0l = b0l; args.b1l = b1l;
  args.h0 = h0; args.h1 = h1; args.hfin = hfin;
  args.wout = wout; args.bout = bout; args.y = y;
  args.cnt = cnt;

  (void)hipFuncSetAttribute((const void*)k_lstm,
                            hipFuncAttributeMaxDynamicSharedMemorySize, 106624);
  void* kp[] = { (void*)&args };
  hipLaunchCooperativeKernel((void*)k_lstm, dim3(NWG), dim3(256), kp, 106624, stream);
}

// Round 14
// 11461.733 us; speedup vs baseline: 2.9699x; 1.2094x over previous
//
#include <hip/hip_runtime.h>
#include <hip/hip_bf16.h>

#define B_ 128
#define T_ 1024
#define I_ 256
#define H_ 1024
#define O_ 128
#define NWG 256
#define HS_ 131072   // ushorts per h slot: [8 rowblk][32 chunk][64 lane][8] = 256KB

typedef __attribute__((ext_vector_type(4))) float f32x4;
typedef __attribute__((ext_vector_type(8))) short s16x8;

__device__ __forceinline__ unsigned short f2bf(float f){
  union { float f; unsigned int u; } a; a.f = f;
  unsigned int r = a.u + 0x7FFFu + ((a.u >> 16) & 1u);
  return (unsigned short)(r >> 16);
}
__device__ __forceinline__ float sigmf(float x){ return 1.f/(1.f+__expf(-x)); }
__device__ __forceinline__ float tanhf_(float x){ return 2.f/(1.f+__expf(-2.f*x)) - 1.f; }

// L3-direct coherent accessors (validated R4/R8/R9/R13)
__device__ __forceinline__ void ld_frag(s16x8 &d, const unsigned short* p){
  asm volatile("global_load_dwordx4 %0, %1, off sc1" : "=v"(d) : "v"(p) : "memory");
}
__device__ __forceinline__ void ld_f4c(f32x4 &d, const float* p){
  asm volatile("global_load_dwordx4 %0, %1, off sc1" : "=v"(d) : "v"(p) : "memory");
}
__device__ __forceinline__ void st_h(unsigned short* p, unsigned short v){
  __hip_atomic_store(p, v, __ATOMIC_RELAXED, __HIP_MEMORY_SCOPE_AGENT);
}
__device__ __forceinline__ void st_f(float* p, float v){
  __hip_atomic_store(p, v, __ATOMIC_RELAXED, __HIP_MEMORY_SCOPE_AGENT);
}

template<int N>
__device__ __forceinline__ void waitpair(s16x8 &x, s16x8 &y){
  if      constexpr (N==14) asm volatile("s_waitcnt vmcnt(14)" : "+v"(x), "+v"(y) :: "memory");
  else if constexpr (N==12) asm volatile("s_waitcnt vmcnt(12)" : "+v"(x), "+v"(y) :: "memory");
  else if constexpr (N==10) asm volatile("s_waitcnt vmcnt(10)" : "+v"(x), "+v"(y) :: "memory");
  else if constexpr (N==8)  asm volatile("s_waitcnt vmcnt(8)"  : "+v"(x), "+v"(y) :: "memory");
  else if constexpr (N==6)  asm volatile("s_waitcnt vmcnt(6)"  : "+v"(x), "+v"(y) :: "memory");
  else if constexpr (N==4)  asm volatile("s_waitcnt vmcnt(4)"  : "+v"(x), "+v"(y) :: "memory");
  else if constexpr (N==2)  asm volatile("s_waitcnt vmcnt(2)"  : "+v"(x), "+v"(y) :: "memory");
  else                      asm volatile("s_waitcnt vmcnt(0)"  : "+v"(x), "+v"(y) :: "memory");
}
__device__ __forceinline__ void vm_drain(){
  asm volatile("s_waitcnt vmcnt(0)" ::: "memory");
}

// ---- sharded grid barrier (R9/R13-validated): one barrier per phase -----
__device__ __forceinline__ void bar_arrive(unsigned* base, int gwg, int tid){
  vm_drain();
  __syncthreads();
  if (tid == 0)
    __hip_atomic_fetch_add(&base[(gwg & 7) << 6], 1u, __ATOMIC_RELAXED, __HIP_MEMORY_SCOPE_AGENT);
}
__device__ __forceinline__ void bar_wait(unsigned* base, unsigned tgt32, int tid){
  if (tid < 8){
    while (__hip_atomic_load(&base[tid << 6], __ATOMIC_RELAXED, __HIP_MEMORY_SCOPE_AGENT) < tgt32)
      __builtin_amdgcn_s_sleep(2);
  }
  __syncthreads();
}

// ---- prep kernels (R4/R13 byte-identical) --------------------------------

__global__ void k_cast_x(const float* __restrict__ x, unsigned short* __restrict__ xb, int n4){
  int i = blockIdx.x*blockDim.x + threadIdx.x;
  if (i >= n4) return;
  f32x4 v = reinterpret_cast<const f32x4*>(x)[i];
  ushort4 o;
  o.x = f2bf(v[0]); o.y = f2bf(v[1]); o.z = f2bf(v[2]); o.w = f2bf(v[3]);
  reinterpret_cast<ushort4*>(xb)[i] = o;
}

// W0cat layout: [wg 256][kblk 160][row 16][8] bf16, k = [w_ih0 (256) | w_hh0 (1024)]
__global__ void k_prep_w0(const float* __restrict__ wih, const float* __restrict__ whh,
                          unsigned short* __restrict__ out){
  int n = blockIdx.x*256 + threadIdx.x;           // 5242880
  int j = n & 7, r = (n >> 3) & 15;
  int t = n >> 7;
  int kb = t % 160, gw = t / 160;
  int k = kb*8 + j;
  int grow = (r >> 2)*H_ + gw*4 + (r & 3);
  float v = (k < I_) ? wih[grow*I_ + k] : whh[grow*H_ + (k - I_)];
  out[n] = f2bf(v);
}

// W1cat layout: [wg 256][kblk 256][row 16][8] bf16, k = [w_ih1 (1024) | w_hh1 (1024)]
__global__ void k_prep_w1(const float* __restrict__ wih, const float* __restrict__ whh,
                          unsigned short* __restrict__ out){
  int n = blockIdx.x*256 + threadIdx.x;           // 8388608
  int j = n & 7, r = (n >> 3) & 15;
  int t = n >> 7;
  int kb = t & 255, gw = t >> 8;
  int k = kb*8 + j;
  int grow = (r >> 2)*H_ + gw*4 + (r & 3);
  float v = (k < H_) ? wih[grow*H_ + k] : whh[grow*H_ + (k - H_)];
  out[n] = f2bf(v);
}

__global__ void k_prep_b(const float* __restrict__ bi0, const float* __restrict__ bh0,
                         const float* __restrict__ bi1, const float* __restrict__ bh1,
                         float* __restrict__ b0, float* __restrict__ b1){
  int n = blockIdx.x*256 + threadIdx.x;           // 8192
  int layer = n >> 12; int rem = n & 4095;
  int gw = rem >> 4, r = rem & 15;
  int grow = (r >> 2)*H_ + gw*4 + (r & 3);
  if (layer == 0) b0[rem] = bi0[grow] + bh0[grow];
  else            b1[rem] = bi1[grow] + bh1[grow];
}

// ---- persistent LSTM kernel --------------------------------------------

struct KArgs {
  const unsigned short* xb;
  const float* x32;
  const unsigned short* w0l;
  const unsigned short* w1l;
  const float* b0l;
  const float* b1l;
  unsigned short* h0;         // [3][HS_] fragment-major ring
  unsigned short* h1;         // [3][HS_]
  float* hfin;                // [B][H] fp32 (linear)
  const float* wout;
  const float* bout;
  float* y;
  unsigned* cnt;              // 8 shards, 256B apart
};

// In-register gate epilogue (R13 verbatim; h stored fragment-major).
__device__ __forceinline__ void epi(f32x4 (&acc)[2], float (&cs)[2][4], float bias,
                                    unsigned short* __restrict__ hw,
                                    float* __restrict__ hfin,
                                    int wv, int lane, int gwg){
  const int u  = lane & 3;
  const int g0 = (lane >> 2) & 3;
  const int bq = lane >> 4;
  const int ug = (gwg << 2) + u;            // global unit 0..1023
  const int kc = ug >> 5;
  const int kg = (ug >> 3) & 3;
  const int jj = ug & 7;
  #pragma unroll
  for (int btl = 0; btl < 2; ++btl){
    const int rb = wv*2 + btl;
    #pragma unroll
    for (int r = 0; r < 4; ++r){
      float pre = acc[btl][r] + bias;
      float q1 = __shfl_xor(pre, 4);
      float q2 = __shfl_xor(pre, 8);
      float q3 = __shfl_xor(pre, 12);
      float iv = (g0==0)?pre:((g0==1)?q1:((g0==2)?q2:q3));
      float fv = (g0==1)?pre:((g0==0)?q1:((g0==3)?q2:q3));
      float gv = (g0==2)?pre:((g0==3)?q1:((g0==0)?q2:q3));
      float ov = (g0==3)?pre:((g0==2)?q1:((g0==1)?q2:q3));
      iv = sigmf(iv); fv = sigmf(fv); gv = tanhf_(gv); ov = sigmf(ov);
      float cn = fv*cs[btl][r] + iv*gv;
      cs[btl][r] = cn;
      float h = ov*tanhf_(cn);
      if (g0 == 0){
        int brow = bq*4 + r;
        int eidx = (((rb*32 + kc) << 9) + (kg*16 + brow)*8 + jj);
        st_h(&hw[eidx], f2bf(h));
        if (hfin) st_f(&hfin[(rb*16 + brow)*H_ + ug], h);
      }
    }
  }
}

#define MFMA_(A, Bf, C) __builtin_amdgcn_mfma_f32_16x16x32_bf16(A, Bf, C, 0, 0, 0)

// Fused step i (0..31): consume h0 chunk i -> acc0 (W0 chunk 8+i) AND acc1
// (W1 chunk i). Reissue slot with h0 chunk i+8 (i<24) or h1 chunk i-24.
#define FUS(i) { \
  const int s_ = (i) & 7; \
  s16x8 w0n_ = wfc, w1n_; \
  if ((i) + 1 < 32) w0n_ = *(const s16x8*)(sW0 + ((9 + (i)) << 9) + (lane << 3)); \
  w1n_ = *(const s16x8*)(sW1 + (((i) + 1) << 9) + (lane << 3)); \
  waitpair<14>(fr[s_][0], fr[s_][1]); \
  acc0[0] = MFMA_(fr[s_][0], wfc, acc0[0]); \
  acc0[1] = MFMA_(fr[s_][1], wfc, acc0[1]); \
  acc1[0] = MFMA_(fr[s_][0], wf1c, acc1[0]); \
  acc1[1] = MFMA_(fr[s_][1], wf1c, acc1[1]); \
  { const int j_ = (i) + 8; \
    const unsigned short* b_ = (j_ < 32) ? h0r : h1r; \
    const int c_ = j_ & 31; \
    ld_frag(fr[s_][0], b_ + ((rdA + c_) << 9) + l8); \
    ld_frag(fr[s_][1], b_ + ((rdB + c_) << 9) + l8); } \
  wfc = w0n_; wf1c = w1n_; }

// Second-loop step (R13 STEP1 shape, shifted index 32+j): h1 chunk j -> acc1
#define ST2(j, NW) { \
  const int s_ = (j) & 7; \
  s16x8 w1n_ = wf1c; \
  if ((j) + 1 < 32) w1n_ = *(const s16x8*)(sW1 + ((33 + (j)) << 9) + (lane << 3)); \
  waitpair<NW>(fr[s_][0], fr[s_][1]); \
  acc1[0] = MFMA_(fr[s_][0], wf1c, acc1[0]); \
  acc1[1] = MFMA_(fr[s_][1], wf1c, acc1[1]); \
  if ((j) + 8 < 32){ const int c_ = (j) + 8; \
    ld_frag(fr[s_][0], h1r + ((rdA + c_) << 9) + l8); \
    ld_frag(fr[s_][1], h1r + ((rdB + c_) << 9) + l8); } \
  wf1c = w1n_; }

__global__ void __launch_bounds__(256, 1) k_lstm(KArgs a){
  extern __shared__ char smem[];
  unsigned short* sW0 = (unsigned short*)smem;             // 40960 B
  unsigned short* sW1 = (unsigned short*)(smem + 40960);   // 65536 B -> 106496
  float* sB    = (float*)(smem + 106496);                  // 32 f -> 106624 total

  const int tid  = threadIdx.x;
  const int gwg  = blockIdx.x;
  const int wv   = tid >> 6;
  const int lane = tid & 63;
  const int lrow = lane & 15;
  const int kgrp = lane >> 4;
  const int koff = kgrp << 3;

  {
    const s16x8* s0 = (const s16x8*)a.w0l + gwg*2560;
    s16x8* d0 = (s16x8*)sW0;
    for (int i = tid; i < 2560; i += 256) d0[i] = s0[i];
    const s16x8* s1 = (const s16x8*)a.w1l + gwg*4096;
    s16x8* d1 = (s16x8*)sW1;
    for (int i = tid; i < 4096; i += 256) d1[i] = s1[i];
    if (tid < 16){ sB[tid] = a.b0l[gwg*16 + tid]; sB[16 + tid] = a.b1l[gwg*16 + tid]; }
  }
  __syncthreads();

  const float bias0 = sB[lrow];
  const float bias1 = sB[16 + lrow];
  float c0s[2][4] = {{0,0,0,0},{0,0,0,0}};
  float c1s[2][4] = {{0,0,0,0},{0,0,0,0}};

  const int rdA = (wv*2 + 0) << 5;   // chunk-block base, rowblk wv*2
  const int rdB = (wv*2 + 1) << 5;   // rowblk wv*2+1
  const int l8  = lane << 3;
  const size_t xoff0 = (size_t)((wv*2 + 0)*16 + lrow)*(T_*I_) + koff;
  const size_t xoff1 = (size_t)((wv*2 + 1)*16 + lrow)*(T_*I_) + koff;
  const f32x4 z = {0.f, 0.f, 0.f, 0.f};

  int m3 = 0, m3p1 = 1, m3p2 = 2;   // R4-proven ring-3

  for (int p = 0; p <= T_; ++p){
    const unsigned short* __restrict__ h0r = a.h0 + m3p2*HS_;  // h0_{p-1}
    const unsigned short* __restrict__ h1r = a.h1 + m3p1*HS_;  // h1_{p-2}
    unsigned short* __restrict__ h0w = a.h0 + m3  *HS_;        // h0_p
    unsigned short* __restrict__ h1w = a.h1 + m3p2*HS_;        // h1_{p-1}

    // ---- L0 x-part hoisted above the wait (R13 verbatim) ----
    f32x4 acc0[2] = {z, z};
    f32x4 acc1[2] = {z, z};
    if (p < T_){
      if (a.xb){
        const unsigned short* xp0 = a.xb + xoff0 + p*I_;
        const unsigned short* xp1 = a.xb + xoff1 + p*I_;
        #pragma unroll
        for (int kc = 0; kc < 8; ++kc){
          s16x8 wf = *(const s16x8*)(sW0 + (kc << 9) + (lane << 3));
          s16x8 a0 = *(const s16x8*)(xp0 + (kc << 5));
          s16x8 a1 = *(const s16x8*)(xp1 + (kc << 5));
          acc0[0] = MFMA_(a0, wf, acc0[0]);
          acc0[1] = MFMA_(a1, wf, acc0[1]);
        }
      } else {
        const float* fx0 = a.x32 + xoff0 + p*I_;
        const float* fx1 = a.x32 + xoff1 + p*I_;
        #pragma unroll
        for (int kc = 0; kc < 8; ++kc){
          s16x8 wf = *(const s16x8*)(sW0 + (kc << 9) + (lane << 3));
          union { s16x8 v; unsigned short us[8]; } t0, t1;
          f32x4 p00 = *(const f32x4*)(fx0 + (kc << 5));
          f32x4 p01 = *(const f32x4*)(fx0 + (kc << 5) + 4);
          f32x4 p10 = *(const f32x4*)(fx1 + (kc << 5));
          f32x4 p11 = *(const f32x4*)(fx1 + (kc << 5) + 4);
          #pragma unroll
          for (int j2 = 0; j2 < 4; ++j2){
            t0.us[j2] = f2bf(p00[j2]); t0.us[4+j2] = f2bf(p01[j2]);
            t1.us[j2] = f2bf(p10[j2]); t1.us[4+j2] = f2bf(p11[j2]);
          }
          acc0[0] = MFMA_(t0.v, wf, acc0[0]);
          acc0[1] = MFMA_(t1.v, wf, acc0[1]);
        }
      }
    }

    // ---- single wait: all WGs completed phase p-1 ----
    if (p > 0) bar_wait(a.cnt, 32u * (unsigned)p, tid);

    // ---- fused pipeline: h0 chunks feed acc0 AND acc1; then h1 -> acc1 ----
    vm_drain();   // counted region must contain only our asm loads
    {
      s16x8 fr[8][2];
      #pragma unroll
      for (int s2 = 0; s2 < 8; ++s2){
        ld_frag(fr[s2][0], h0r + ((rdA + s2) << 9) + l8);
        ld_frag(fr[s2][1], h0r + ((rdB + s2) << 9) + l8);
      }
      s16x8 wfc  = *(const s16x8*)(sW0 + (8 << 9) + (lane << 3));
      s16x8 wf1c = *(const s16x8*)(sW1 + (lane << 3));
      #pragma unroll
      for (int i = 0; i < 32; ++i) FUS(i);
      if (p < T_) epi(acc0, c0s, bias0, h0w, nullptr, wv, lane, gwg);
      #pragma unroll
      for (int j = 0; j < 24; ++j) ST2(j, 14);
      ST2(24,14); ST2(25,12); ST2(26,10); ST2(27,8);
      ST2(28,6);  ST2(29,4);  ST2(30,2);  ST2(31,0);
      if (p > 0) epi(acc1, c1s, bias1, h1w, (p == T_) ? a.hfin : nullptr, wv, lane, gwg);
    }

    bar_arrive(a.cnt, gwg, tid);     // single end-of-phase publish

    m3 = m3p1; m3p1 = m3p2; m3p2 = (m3p2 == 2) ? 0 : m3p2 + 1;
  }

  bar_wait(a.cnt, 32u * (unsigned)(T_ + 1), tid);

  // output: y = h_last @ w_out^T + b_out (fp32) on WGs 0..63 (R13 verbatim)
  if (gwg < 64){
    const int b = (gwg >> 3)*16 + (tid >> 4);
    const int o = (gwg & 7)*16 + (tid & 15);
    const float* hb = a.hfin + b*H_;
    const f32x4* wr = (const f32x4*)(a.wout + o*H_);
    float s = a.bout[o];
    for (int g = 0; g < 32; ++g){
      f32x4 t0,t1,t2,t3,t4,t5,t6,t7;
      ld_f4c(t0, hb + g*32 +  0); ld_f4c(t1, hb + g*32 +  4);
      ld_f4c(t2, hb + g*32 +  8); ld_f4c(t3, hb + g*32 + 12);
      ld_f4c(t4, hb + g*32 + 16); ld_f4c(t5, hb + g*32 + 20);
      ld_f4c(t6, hb + g*32 + 24); ld_f4c(t7, hb + g*32 + 28);
      asm volatile("s_waitcnt vmcnt(0)"
        : "+v"(t0),"+v"(t1),"+v"(t2),"+v"(t3),"+v"(t4),"+v"(t5),"+v"(t6),"+v"(t7) :: "memory");
      const f32x4 w0 = wr[g*8+0], w1 = wr[g*8+1], w2 = wr[g*8+2], w3 = wr[g*8+3];
      const f32x4 w4 = wr[g*8+4], w5 = wr[g*8+5], w6 = wr[g*8+6], w7 = wr[g*8+7];
      s += t0[0]*w0[0]+t0[1]*w0[1]+t0[2]*w0[2]+t0[3]*w0[3];
      s += t1[0]*w1[0]+t1[1]*w1[1]+t1[2]*w1[2]+t1[3]*w1[3];
      s += t2[0]*w2[0]+t2[1]*w2[1]+t2[2]*w2[2]+t2[3]*w2[3];
      s += t3[0]*w3[0]+t3[1]*w3[1]+t3[2]*w3[2]+t3[3]*w3[3];
      s += t4[0]*w4[0]+t4[1]*w4[1]+t4[2]*w4[2]+t4[3]*w4[3];
      s += t5[0]*w5[0]+t5[1]*w5[1]+t5[2]*w5[2]+t5[3]*w5[3];
      s += t6[0]*w6[0]+t6[1]*w6[1]+t6[2]*w6[2]+t6[3]*w6[3];
      s += t7[0]*w7[0]+t7[1]*w7[1]+t7[2]*w7[2]+t7[3]*w7[3];
    }
    a.y[b*O_ + o] = s;
  }
}

// ---- host ---------------------------------------------------------------

extern "C" void kernel_launch(void* const* d_in, const int* in_sizes, int n_in,
                              void* d_out, int out_size, void* d_ws, size_t ws_size,
                              hipStream_t stream){
  const float* x    = (const float*)d_in[0];
  const float* wih0 = (const float*)d_in[1];
  const float* whh0 = (const float*)d_in[2];
  const float* bih0 = (const float*)d_in[3];
  const float* bhh0 = (const float*)d_in[4];
  const float* wih1 = (const float*)d_in[5];
  const float* whh1 = (const float*)d_in[6];
  const float* bih1 = (const float*)d_in[7];
  const float* bhh1 = (const float*)d_in[8];
  const float* wout = (const float*)d_in[9];
  const float* bout = (const float*)d_in[10];
  float* y = (float*)d_out;

  char* ws = (char*)d_ws;
  size_t off = 0;
  auto alloc = [&](size_t n){ char* p = ws + off; off += (n + 255) & ~(size_t)255; return p; };

  unsigned* cnt = (unsigned*)alloc(2048);           // 8 shards, 256B apart
  unsigned short* w0l = (unsigned short*)alloc((size_t)256*160*16*8*2);
  unsigned short* w1l = (unsigned short*)alloc((size_t)256*256*16*8*2);
  float* b0l  = (float*)alloc(256*16*4);
  float* b1l  = (float*)alloc(256*16*4);
  unsigned short* h0 = (unsigned short*)alloc((size_t)3*HS_*2);
  unsigned short* h1 = (unsigned short*)alloc((size_t)3*HS_*2);
  float* hfin = (float*)alloc((size_t)B_*H_*4);
  unsigned short* xb = nullptr;
  size_t xb_bytes = (size_t)B_*T_*I_*2;
  if (ws_size >= off + xb_bytes + 256) xb = (unsigned short*)alloc(xb_bytes);

  hipMemsetAsync(cnt, 0, 2048, stream);
  hipMemsetAsync(h0, 0, (size_t)3*HS_*2, stream);
  hipMemsetAsync(h1, 0, (size_t)3*HS_*2, stream);

  if (xb) k_cast_x<<<dim3((B_*T_*I_/4 + 255)/256), dim3(256), 0, stream>>>(x, xb, B_*T_*I_/4);
  k_prep_w0<<<dim3(5242880/256), dim3(256), 0, stream>>>(wih0, whh0, w0l);
  k_prep_w1<<<dim3(8388608/256), dim3(256), 0, stream>>>(wih1, whh1, w1l);
  k_prep_b<<<dim3(32), dim3(256), 0, stream>>>(bih0, bhh0, bih1, bhh1, b0l, b1l);

  KArgs args;
  args.xb = xb; args.x32 = x;
  args.w0l = w0l; args.w1l = w1l; args.b0l = b0l; args.b1l = b1l;
  args.h0 = h0; args.h1 = h1; args.hfin = hfin;
  args.wout = wout; args.bout = bout; args.y = y;
  args.cnt = cnt;

  (void)hipFuncSetAttribute((const void*)k_lstm,
                            hipFuncAttributeMaxDynamicSharedMemorySize, 106624);
  void* kp[] = { (void*)&args };
  hipError_t e = hipLaunchCooperativeKernel((void*)k_lstm, dim3(NWG), dim3(256),
                                            kp, 106624, stream);
  if (e != hipSuccess){
    // rescue: plain launch (no cg in kernel; grid == CU count => co-resident)
    k_lstm<<<dim3(NWG), dim3(256), 106624, stream>>>(args);
  }
}